// Round 1
// baseline (271.674 us; speedup 1.0000x reference)
//
#include <hip/hip_runtime.h>

typedef __attribute__((ext_vector_type(4))) int int4v;
typedef __attribute__((ext_vector_type(16))) int int16v;

#define NPIX 100352      // 32*56*56
#define PPIX 107648      // 32*58*58 zero-padded pixels
#define KTAP 2304        // 9*256
#define LDK 144          // 128 + 16 pad (16B aligned, measured 0 bank conflicts)
#define BSZ (256 * LDK)  // one B stage buffer: 36,864 B

// ---------- kernel 1: weight sign transpose (coalesced reads, LDS transpose) ----------
__global__ __launch_bounds__(256) void quant_w_kernel(const float* __restrict__ Wm,
                                                      signed char* __restrict__ Bt,
                                                      float* __restrict__ Esum) {
  __shared__ signed char sT[64][80];   // [cout][k] tile, row stride 80 (16B aligned)
  __shared__ float red[4];
  const int k0 = blockIdx.x * 64;      // 36 tiles in k
  const int c0 = blockIdx.y * 64;      // 4 tiles in cout
  const int t = threadIdx.x;
  const int cc = t & 63;
  const int r0 = (t >> 6) * 16;
  float s = 0.f;
#pragma unroll
  for (int i = 0; i < 16; ++i) {
    const int k = r0 + i;
    float w = Wm[(long)(k0 + k) * 256 + c0 + cc];   // coalesced over cc
    s += fabsf(w);
    sT[cc][k] = (signed char)((w > 0.f) ? 1 : ((w < 0.f) ? -1 : 0));
  }
#pragma unroll
  for (int o = 32; o > 0; o >>= 1) s += __shfl_down(s, o, 64);
  if ((t & 63) == 0) red[t >> 6] = s;
  __syncthreads();
  if (t == 0) atomicAdd(Esum, red[0] + red[1] + red[2] + red[3]);
  const int co = t >> 2;
  const int kc = (t & 3) * 16;
  int4v v = *(const int4v*)&sT[co][kc];
  *(int4v*)(Bt + (long)(c0 + co) * KTAP + k0 + kc) = v;
}

// ---------- kernel 2: activation quantize fp32 -> int8 {0..7}, zero-padded 58x58 layout ----------
__global__ __launch_bounds__(256) void quant_x_kernel(const float* __restrict__ x,
                                                      signed char* __restrict__ xq) {
  const int tid = blockIdx.x * 256 + threadIdx.x;   // 6,889,472 threads = PPIX*256/4
  const int ci = tid & 63;                          // channel chunk (4 ch)
  const int pix = tid >> 6;                         // padded pixel index
  const int q1 = pix / 58;
  const int wp = pix - q1 * 58;
  const int n = q1 / 58;
  const int hp = q1 - n * 58;
  unsigned int qv = 0;
  if ((unsigned)(hp - 1) < 56u && (unsigned)(wp - 1) < 56u) {
    const int src = n * 3136 + (hp - 1) * 56 + (wp - 1);
    float4 v = ((const float4*)x)[src * 64 + ci];   // 64 threads -> 1KB contiguous
    qv  = (unsigned int)(int)rintf(fminf(1.f, fabsf(v.x)) * 7.f);
    qv |= ((unsigned int)(int)rintf(fminf(1.f, fabsf(v.y)) * 7.f)) << 8;
    qv |= ((unsigned int)(int)rintf(fminf(1.f, fabsf(v.z)) * 7.f)) << 16;
    qv |= ((unsigned int)(int)rintf(fminf(1.f, fabsf(v.w)) * 7.f)) << 24;
  }
  ((unsigned int*)xq)[tid] = qv;                    // halo pixels get 0
}

// byte shift into padded xq for K-stage u (tap = u>>1, K-half = u&1)
__device__ __forceinline__ int tap_shift(int u) {
  const int tp = u >> 1;
  return ((tp / 3 - 1) * 58 + (tp % 3) - 1) * 256 + (u & 1) * 128;
}

// ---------- kernel 3: implicit-GEMM conv ----------
// BM=128 BN=256 BK=128. A fragments direct from global (padded xq, L2-resident);
// B double-buffered in LDS, ONE raw s_barrier per K-stage, loads in flight across it.
__global__ __launch_bounds__(256, 2) void conv_kernel(const signed char* __restrict__ xq,
                                                      const signed char* __restrict__ Bt,
                                                      const float* __restrict__ bias,
                                                      const float* __restrict__ Esum,
                                                      float* __restrict__ out) {
  __shared__ signed char Bs[2 * BSZ];   // 73,728 B -> 2 blocks/CU

  const int t = threadIdx.x;
  const int lane = t & 63;
  const int wid = t >> 6;
  // bijective XCD swizzle: 784 = 8 * 98 -> each XCD gets 98 contiguous M-tiles
  const int bid = blockIdx.x;
  const int tile = (bid & 7) * 98 + (bid >> 3);
  const int m0 = tile * 128;
  const int wm = (wid & 1) * 64;           // wave tile: 64 rows x 128 cols
  const int wn = (wid >> 1) * 128;
  const int lrow = lane & 31;
  const int khalf = (lane >> 5) * 16;

  // padded byte base for this lane's two A rows (includes khalf)
  int pb0, pb1;
  {
    const int p0 = m0 + wm + lrow;
    const int n0 = p0 / 3136, r0 = p0 - n0 * 3136;
    const int h0 = r0 / 56, w0 = r0 - h0 * 56;
    pb0 = ((n0 * 58 + h0 + 1) * 58 + (w0 + 1)) * 256 + khalf;
    const int p1 = p0 + 32;
    const int n1 = p1 / 3136, r1 = p1 - n1 * 3136;
    const int h1 = r1 / 56, w1 = r1 - h1 * 56;
    pb1 = ((n1 * 58 + h1 + 1) * 58 + (w1 + 1)) * 256 + khalf;
  }

  // B staging: 8 threads cover one 128B row chunk (coalesced), rows t>>3 + 32*i
  const int brow = t >> 3;
  const int bcol = (t & 7) * 16;
  const int gb = brow * KTAP + bcol;
  const int lb = brow * LDK + bcol;

  int16v acc[2][4];
#pragma unroll
  for (int a = 0; a < 2; ++a)
#pragma unroll
    for (int b = 0; b < 4; ++b)
#pragma unroll
      for (int r = 0; r < 16; ++r) acc[a][b][r] = 0;

  // ---- prologue: A(s=0,ks=0) fragments + B(0) staged + B(1) in flight ----
  int4v raA0 = *(const int4v*)(xq + pb0 + tap_shift(0));
  int4v raA1 = *(const int4v*)(xq + pb1 + tap_shift(0));
  int4v rb[8];
#pragma unroll
  for (int i = 0; i < 8; ++i) rb[i] = *(const int4v*)(Bt + gb + i * (32 * KTAP));
#pragma unroll
  for (int i = 0; i < 8; ++i) *(int4v*)(Bs + lb + i * (32 * LDK)) = rb[i];
#pragma unroll
  for (int i = 0; i < 8; ++i) rb[i] = *(const int4v*)(Bt + gb + 128 + i * (32 * KTAP));
  asm volatile("s_waitcnt lgkmcnt(0)" ::: "memory");
  __builtin_amdgcn_s_barrier();
  __builtin_amdgcn_sched_barrier(0);

  for (int s = 0; s < 18; ++s) {
    const int ash = tap_shift(s);
    const int ashN = tap_shift(s < 17 ? s + 1 : 17);   // clamp keeps addresses in-bounds
    signed char* Bcur = Bs + (s & 1) * BSZ;
    signed char* Bnxt = Bs + ((~s) & 1) * BSZ;
    const signed char* a0p = xq + pb0 + ash;
    const signed char* a1p = xq + pb1 + ash;
    const signed char* n0p = xq + pb0 + ashN;
    const signed char* n1p = xq + pb1 + ashN;

    // write B(s+1) (loaded a full stage ago; counted vmcnt, no drain)
    if (s + 1 < 18) {
#pragma unroll
      for (int i = 0; i < 8; ++i) *(int4v*)(Bnxt + lb + i * (32 * LDK)) = rb[i];
    }
    // issue B(s+2) loads — consumed only after the NEXT barrier
    if (s + 2 < 18) {
      const int ko2 = (s + 2) * 128;
#pragma unroll
      for (int i = 0; i < 8; ++i) rb[i] = *(const int4v*)(Bt + gb + ko2 + i * (32 * KTAP));
    }

#pragma unroll
    for (int ks = 0; ks < 4; ++ks) {
      // prefetch next A pair (ks+1, or ks=0 of next stage across the barrier)
      int4v nx0 = *(const int4v*)((ks < 3) ? (a0p + (ks + 1) * 32) : n0p);
      int4v nx1 = *(const int4v*)((ks < 3) ? (a1p + (ks + 1) * 32) : n1p);
      const int ko = ks * 32 + khalf;
      int4v b0 = *(const int4v*)(Bcur + (wn + lrow) * LDK + ko);
      int4v b1 = *(const int4v*)(Bcur + (wn + 32 + lrow) * LDK + ko);
      int4v b2 = *(const int4v*)(Bcur + (wn + 64 + lrow) * LDK + ko);
      int4v b3 = *(const int4v*)(Bcur + (wn + 96 + lrow) * LDK + ko);
      __builtin_amdgcn_s_setprio(1);
      acc[0][0] = __builtin_amdgcn_mfma_i32_32x32x32_i8(raA0, b0, acc[0][0], 0, 0, 0);
      acc[0][1] = __builtin_amdgcn_mfma_i32_32x32x32_i8(raA0, b1, acc[0][1], 0, 0, 0);
      acc[0][2] = __builtin_amdgcn_mfma_i32_32x32x32_i8(raA0, b2, acc[0][2], 0, 0, 0);
      acc[0][3] = __builtin_amdgcn_mfma_i32_32x32x32_i8(raA0, b3, acc[0][3], 0, 0, 0);
      acc[1][0] = __builtin_amdgcn_mfma_i32_32x32x32_i8(raA1, b0, acc[1][0], 0, 0, 0);
      acc[1][1] = __builtin_amdgcn_mfma_i32_32x32x32_i8(raA1, b1, acc[1][1], 0, 0, 0);
      acc[1][2] = __builtin_amdgcn_mfma_i32_32x32x32_i8(raA1, b2, acc[1][2], 0, 0, 0);
      acc[1][3] = __builtin_amdgcn_mfma_i32_32x32x32_i8(raA1, b3, acc[1][3], 0, 0, 0);
      __builtin_amdgcn_s_setprio(0);
      raA0 = nx0; raA1 = nx1;
    }

    if (s < 17) {
      // flush ds_writes, then raw barrier (NO vmcnt drain — global loads stay in flight)
      asm volatile("s_waitcnt lgkmcnt(0)" ::: "memory");
      __builtin_amdgcn_sched_barrier(0);
      __builtin_amdgcn_s_barrier();
      __builtin_amdgcn_sched_barrier(0);
    }
  }

  // epilogue: out = acc * (E/7) + bias
  const float scale = Esum[0] * (1.0f / (589824.0f * 7.0f));
#pragma unroll
  for (int mt = 0; mt < 2; ++mt)
#pragma unroll
    for (int nt = 0; nt < 4; ++nt) {
      const int col = wn + nt * 32 + lrow;
      const float bv = bias[col];
#pragma unroll
      for (int r = 0; r < 16; ++r) {
        const int row = (r & 3) + 8 * (r >> 2) + 4 * (lane >> 5);
        const int m = m0 + wm + mt * 32 + row;
        out[(long)m * 256 + col] = (float)acc[mt][nt][r] * scale + bv;
      }
    }
}

extern "C" void kernel_launch(void* const* d_in, const int* in_sizes, int n_in,
                              void* d_out, int out_size, void* d_ws, size_t ws_size,
                              hipStream_t stream) {
  const float* x    = (const float*)d_in[0];
  const float* Wm   = (const float*)d_in[1];
  const float* bias = (const float*)d_in[2];
  float* out = (float*)d_out;

  float* Esum = (float*)d_ws;
  signed char* Bt = (signed char*)d_ws + 256;                 // 589,824 B
  signed char* xq = (signed char*)d_ws + 256 + 589824;        // 27,557,888 B (padded)

  hipMemsetAsync(d_ws, 0, 4, stream);
  quant_w_kernel<<<dim3(36, 4), 256, 0, stream>>>(Wm, Bt, Esum);
  quant_x_kernel<<<26912, 256, 0, stream>>>(x, xq);
  conv_kernel<<<784, 256, 0, stream>>>(xq, Bt, bias, Esum, out);
}

// Round 3
// 265.275 us; speedup vs baseline: 1.0241x; 1.0241x over previous
//
#include <hip/hip_runtime.h>

typedef __attribute__((ext_vector_type(4))) int int4v;
typedef __attribute__((ext_vector_type(16))) int int16v;

#define NPIX 100352      // 32*56*56
#define PPIX 107648      // 32*58*58 zero-padded pixels
#define KTAP 2304        // 9*256
#define LDK 144          // 128 + 16 pad (16B aligned, measured 0 bank conflicts)
#define BSZ (256 * LDK)  // one B stage buffer: 36,864 B
#define CHB (PPIX * 16)  // bytes per 16-channel chunk plane: 1,722,368 (int-safe)

// ---------- kernel 1: weight sign transpose (coalesced reads, LDS transpose) ----------
__global__ __launch_bounds__(256) void quant_w_kernel(const float* __restrict__ Wm,
                                                      signed char* __restrict__ Bt,
                                                      float* __restrict__ Esum) {
  __shared__ signed char sT[64][80];   // [cout][k] tile, row stride 80 (16B aligned)
  __shared__ float red[4];
  const int k0 = blockIdx.x * 64;      // 36 tiles in k
  const int c0 = blockIdx.y * 64;      // 4 tiles in cout
  const int t = threadIdx.x;
  const int cc = t & 63;
  const int r0 = (t >> 6) * 16;
  float s = 0.f;
#pragma unroll
  for (int i = 0; i < 16; ++i) {
    const int k = r0 + i;
    float w = Wm[(long)(k0 + k) * 256 + c0 + cc];   // coalesced over cc
    s += fabsf(w);
    sT[cc][k] = (signed char)((w > 0.f) ? 1 : ((w < 0.f) ? -1 : 0));
  }
#pragma unroll
  for (int o = 32; o > 0; o >>= 1) s += __shfl_down(s, o, 64);
  if ((t & 63) == 0) red[t >> 6] = s;
  __syncthreads();
  if (t == 0) atomicAdd(Esum, red[0] + red[1] + red[2] + red[3]);
  const int co = t >> 2;
  const int kc = (t & 3) * 16;
  int4v v = *(const int4v*)&sT[co][kc];
  *(int4v*)(Bt + (long)(c0 + co) * KTAP + k0 + kc) = v;
}

// ---------- kernel 2: quantize fp32 -> int8 {0..7}, CHUNK-MAJOR padded layout ----------
// xqT[c][pix] : c = channel/16 (16 planes), each pixel contributes 16 contiguous bytes.
// Lane reads one full 64B cache line (4 float4 of its pixel's 16 channels); writes 16B
// contiguous across lanes (1KB/wave). Halo pixels get zeros.
__global__ __launch_bounds__(256) void quant_x_kernel(const float* __restrict__ x,
                                                      signed char* __restrict__ xqT) {
  const int pix = blockIdx.x * 256 + threadIdx.x;
  if (pix >= PPIX) return;
  const int c = blockIdx.y;                      // chunk 0..15
  const int q1 = pix / 58;
  const int wp = pix - q1 * 58;
  const int n  = q1 / 58;
  const int hp = q1 - n * 58;
  int4v out = {0, 0, 0, 0};
  if ((unsigned)(hp - 1) < 56u && (unsigned)(wp - 1) < 56u) {
    const int src = n * 3136 + (hp - 1) * 56 + (wp - 1);
    const float4* px = (const float4*)(x + (long)src * 256 + c * 16);
#pragma unroll
    for (int j = 0; j < 4; ++j) {
      float4 v = px[j];
      unsigned q;
      q  = (unsigned)(int)rintf(fminf(1.f, fabsf(v.x)) * 7.f);
      q |= ((unsigned)(int)rintf(fminf(1.f, fabsf(v.y)) * 7.f)) << 8;
      q |= ((unsigned)(int)rintf(fminf(1.f, fabsf(v.z)) * 7.f)) << 16;
      q |= ((unsigned)(int)rintf(fminf(1.f, fabsf(v.w)) * 7.f)) << 24;
      out[j] = (int)q;
    }
  }
  *(int4v*)(xqT + (long)c * CHB + pix * 16) = out;
}

// byte shift helpers live inside conv_kernel (see aptr lambda)

// ---------- kernel 3: implicit-GEMM conv ----------
// BM=128 BN=256 BK=128. A fragments direct from global (chunk-major xqT -> coalesced);
// B double-buffered in LDS, ONE raw s_barrier per K-stage, loads in flight across it.
__global__ __launch_bounds__(256, 2) void conv_kernel(const signed char* __restrict__ xqT,
                                                      const signed char* __restrict__ Bt,
                                                      const float* __restrict__ bias,
                                                      const float* __restrict__ Esum,
                                                      float* __restrict__ out) {
  __shared__ signed char Bs[2 * BSZ];   // 73,728 B -> 2 blocks/CU

  const int t = threadIdx.x;
  const int lane = t & 63;
  const int wid = t >> 6;
  // bijective XCD swizzle: 784 = 8 * 98 -> each XCD gets 98 contiguous M-tiles
  const int bid = blockIdx.x;
  const int tile = (bid & 7) * 98 + (bid >> 3);
  const int m0 = tile * 128;
  const int wm = (wid & 1) * 64;           // wave tile: 64 rows x 128 cols
  const int wn = (wid >> 1) * 128;
  const int lrow = lane & 31;
  const int half = lane >> 5;              // which 16B K-chunk of the 32-K block

  // padded pixel indices for this lane's two A rows
  int pp0, pp1;
  {
    const int p0 = m0 + wm + lrow;
    const int n0 = p0 / 3136, r0 = p0 - n0 * 3136;
    const int h0 = r0 / 56, w0 = r0 - h0 * 56;
    pp0 = (n0 * 58 + h0 + 1) * 58 + (w0 + 1);
    const int p1 = p0 + 32;
    const int n1 = p1 / 3136, r1 = p1 - n1 * 3136;
    const int h1 = r1 / 56, w1 = r1 - h1 * 56;
    pp1 = (n1 * 58 + h1 + 1) * 58 + (w1 + 1);
  }

  // A pointer for K-stage u (tap = u>>1, K-half = u&1), given padded pixel pp.
  // chunk plane = (u&1)*8 + half; pixel shift = tap displacement.
  auto aptr = [&](int u, int pp) -> const signed char* {
    const int tp = u >> 1;
    const int dp = (tp / 3 - 1) * 58 + (tp % 3) - 1;
    return xqT + (((u & 1) * 8 + half) * PPIX + pp + dp) * 16;
  };
  const int ks_step = 2 * CHB;   // bytes between consecutive ks chunk planes

  // B staging: 8 threads cover one 128B row chunk (coalesced), rows t>>3 + 32*i
  const int brow = t >> 3;
  const int bcol = (t & 7) * 16;
  const int gb = brow * KTAP + bcol;
  const int lb = brow * LDK + bcol;

  int16v acc[2][4];
#pragma unroll
  for (int a = 0; a < 2; ++a)
#pragma unroll
    for (int b = 0; b < 4; ++b)
#pragma unroll
      for (int r = 0; r < 16; ++r) acc[a][b][r] = 0;

  // ---- prologue: A(s=0,ks=0) fragments + B(0) staged + B(1) in flight ----
  int4v raA0 = *(const int4v*)aptr(0, pp0);
  int4v raA1 = *(const int4v*)aptr(0, pp1);
  int4v rb[8];
#pragma unroll
  for (int i = 0; i < 8; ++i) rb[i] = *(const int4v*)(Bt + gb + i * (32 * KTAP));
#pragma unroll
  for (int i = 0; i < 8; ++i) *(int4v*)(Bs + lb + i * (32 * LDK)) = rb[i];
#pragma unroll
  for (int i = 0; i < 8; ++i) rb[i] = *(const int4v*)(Bt + gb + 128 + i * (32 * KTAP));
  asm volatile("s_waitcnt lgkmcnt(0)" ::: "memory");
  __builtin_amdgcn_s_barrier();
  __builtin_amdgcn_sched_barrier(0);

  for (int s = 0; s < 18; ++s) {
    signed char* Bcur = Bs + (s & 1) * BSZ;
    signed char* Bnxt = Bs + ((~s) & 1) * BSZ;
    const signed char* a0p = aptr(s, pp0);
    const signed char* a1p = aptr(s, pp1);
    const signed char* n0p = aptr(s < 17 ? s + 1 : 17, pp0);  // clamp keeps in-bounds
    const signed char* n1p = aptr(s < 17 ? s + 1 : 17, pp1);

    // write B(s+1) (loaded a full stage ago; counted vmcnt, no drain)
    if (s + 1 < 18) {
#pragma unroll
      for (int i = 0; i < 8; ++i) *(int4v*)(Bnxt + lb + i * (32 * LDK)) = rb[i];
    }
    // issue B(s+2) loads — consumed only after the NEXT barrier
    if (s + 2 < 18) {
      const int ko2 = (s + 2) * 128;
#pragma unroll
      for (int i = 0; i < 8; ++i) rb[i] = *(const int4v*)(Bt + gb + ko2 + i * (32 * KTAP));
    }

#pragma unroll
    for (int ks = 0; ks < 4; ++ks) {
      // prefetch next A pair (ks+1, or ks=0 of next stage across the barrier)
      int4v nx0 = *(const int4v*)((ks < 3) ? (a0p + (ks + 1) * ks_step) : n0p);
      int4v nx1 = *(const int4v*)((ks < 3) ? (a1p + (ks + 1) * ks_step) : n1p);
      const int ko = ks * 32 + half * 16;
      int4v b0 = *(const int4v*)(Bcur + (wn + lrow) * LDK + ko);
      int4v b1 = *(const int4v*)(Bcur + (wn + 32 + lrow) * LDK + ko);
      int4v b2 = *(const int4v*)(Bcur + (wn + 64 + lrow) * LDK + ko);
      int4v b3 = *(const int4v*)(Bcur + (wn + 96 + lrow) * LDK + ko);
      __builtin_amdgcn_s_setprio(1);
      acc[0][0] = __builtin_amdgcn_mfma_i32_32x32x32_i8(raA0, b0, acc[0][0], 0, 0, 0);
      acc[0][1] = __builtin_amdgcn_mfma_i32_32x32x32_i8(raA0, b1, acc[0][1], 0, 0, 0);
      acc[0][2] = __builtin_amdgcn_mfma_i32_32x32x32_i8(raA0, b2, acc[0][2], 0, 0, 0);
      acc[0][3] = __builtin_amdgcn_mfma_i32_32x32x32_i8(raA0, b3, acc[0][3], 0, 0, 0);
      acc[1][0] = __builtin_amdgcn_mfma_i32_32x32x32_i8(raA1, b0, acc[1][0], 0, 0, 0);
      acc[1][1] = __builtin_amdgcn_mfma_i32_32x32x32_i8(raA1, b1, acc[1][1], 0, 0, 0);
      acc[1][2] = __builtin_amdgcn_mfma_i32_32x32x32_i8(raA1, b2, acc[1][2], 0, 0, 0);
      acc[1][3] = __builtin_amdgcn_mfma_i32_32x32x32_i8(raA1, b3, acc[1][3], 0, 0, 0);
      __builtin_amdgcn_s_setprio(0);
      raA0 = nx0; raA1 = nx1;
    }

    if (s < 17) {
      // flush ds_writes, then raw barrier (NO vmcnt drain — global loads stay in flight)
      asm volatile("s_waitcnt lgkmcnt(0)" ::: "memory");
      __builtin_amdgcn_sched_barrier(0);
      __builtin_amdgcn_s_barrier();
      __builtin_amdgcn_sched_barrier(0);
    }
  }

  // epilogue: out = acc * (E/7) + bias
  const float scale = Esum[0] * (1.0f / (589824.0f * 7.0f));
#pragma unroll
  for (int mt = 0; mt < 2; ++mt)
#pragma unroll
    for (int nt = 0; nt < 4; ++nt) {
      const int col = wn + nt * 32 + lrow;
      const float bv = bias[col];
#pragma unroll
      for (int r = 0; r < 16; ++r) {
        const int row = (r & 3) + 8 * (r >> 2) + 4 * (lane >> 5);
        const int m = m0 + wm + mt * 32 + row;
        out[(long)m * 256 + col] = (float)acc[mt][nt][r] * scale + bv;
      }
    }
}

extern "C" void kernel_launch(void* const* d_in, const int* in_sizes, int n_in,
                              void* d_out, int out_size, void* d_ws, size_t ws_size,
                              hipStream_t stream) {
  const float* x    = (const float*)d_in[0];
  const float* Wm   = (const float*)d_in[1];
  const float* bias = (const float*)d_in[2];
  float* out = (float*)d_out;

  float* Esum = (float*)d_ws;
  signed char* Bt = (signed char*)d_ws + 256;                 // 589,824 B
  signed char* xqT = (signed char*)d_ws + 256 + 589824;       // 27,557,888 B (padded, chunk-major)

  hipMemsetAsync(d_ws, 0, 4, stream);
  quant_w_kernel<<<dim3(36, 4), 256, 0, stream>>>(Wm, Bt, Esum);
  quant_x_kernel<<<dim3(421, 16), 256, 0, stream>>>(x, xqT);
  conv_kernel<<<784, 256, 0, stream>>>(xqT, Bt, bias, Esum, out);
}

// Round 4
// 251.957 us; speedup vs baseline: 1.0783x; 1.0529x over previous
//
#include <hip/hip_runtime.h>

typedef __attribute__((ext_vector_type(4))) int int4v;
typedef __attribute__((ext_vector_type(16))) int int16v;

#define NPIX 100352      // 32*56*56
#define PPIX 107648      // 32*58*58 zero-padded pixels
#define KTAP 2304        // 9*256
#define CHB (PPIX * 16)  // bytes per 16-channel chunk plane: 1,722,368
#define LDB 272          // 256 + 16 pad (16B aligned)
#define BTILE (128 * LDB) // 34,816 B single B buffer -> 3 blocks/CU fits LDS easily

// ---------- kernel 1: weight sign transpose (coalesced reads, LDS transpose) ----------
__global__ __launch_bounds__(256) void quant_w_kernel(const float* __restrict__ Wm,
                                                      signed char* __restrict__ Bt,
                                                      float* __restrict__ Esum) {
  __shared__ signed char sT[64][80];
  __shared__ float red[4];
  const int k0 = blockIdx.x * 64;
  const int c0 = blockIdx.y * 64;
  const int t = threadIdx.x;
  const int cc = t & 63;
  const int r0 = (t >> 6) * 16;
  float s = 0.f;
#pragma unroll
  for (int i = 0; i < 16; ++i) {
    const int k = r0 + i;
    float w = Wm[(long)(k0 + k) * 256 + c0 + cc];
    s += fabsf(w);
    sT[cc][k] = (signed char)((w > 0.f) ? 1 : ((w < 0.f) ? -1 : 0));
  }
#pragma unroll
  for (int o = 32; o > 0; o >>= 1) s += __shfl_down(s, o, 64);
  if ((t & 63) == 0) red[t >> 6] = s;
  __syncthreads();
  if (t == 0) atomicAdd(Esum, red[0] + red[1] + red[2] + red[3]);
  const int co = t >> 2;
  const int kc = (t & 3) * 16;
  int4v v = *(const int4v*)&sT[co][kc];
  *(int4v*)(Bt + (long)(c0 + co) * KTAP + k0 + kc) = v;
}

// ---------- kernel 2: quantize fp32 -> int8 {0..7}, chunk-major padded planes ----------
// Read side COALESCED (thread = one float4, contiguous across lanes, same as baseline).
// Write side scatters 4B words into 16 planes (27.5 MB total - cheap side).
// Halo pixels pre-zeroed by memset in kernel_launch.
__global__ __launch_bounds__(256) void quant_x_kernel(const float* __restrict__ x,
                                                      signed char* __restrict__ xqT) {
  const int tid = blockIdx.x * 256 + threadIdx.x;   // 6,422,528 threads
  float4 v = ((const float4*)x)[tid];
  unsigned q;
  q  = (unsigned)(int)rintf(fminf(1.f, fabsf(v.x)) * 7.f);
  q |= ((unsigned)(int)rintf(fminf(1.f, fabsf(v.y)) * 7.f)) << 8;
  q |= ((unsigned)(int)rintf(fminf(1.f, fabsf(v.z)) * 7.f)) << 16;
  q |= ((unsigned)(int)rintf(fminf(1.f, fabsf(v.w)) * 7.f)) << 24;
  const int pix = tid >> 6;
  const int l = tid & 63;
  const int n = pix / 3136;
  const int rem = pix - n * 3136;
  const int h = rem / 56, w = rem - (rem / 56) * 56;
  const int pp = (n * 58 + h + 1) * 58 + (w + 1);
  const int c = l >> 2, j = l & 3;
  *(unsigned*)(xqT + (long)c * CHB + pp * 16 + j * 4) = q;
}

// ---------- kernel 3: implicit-GEMM conv ----------
// BM=128 BN=128 BK=256 (one 3x3 tap per stage, 9 stages). Wave tile 64x64 -> acc=64 AGPR,
// ~160 total regs -> 3 blocks/CU (12 waves). A direct from global chunk-major planes;
// B single-buffered in LDS, 2 raw barriers/stage, global loads never drained.
__global__ __launch_bounds__(256, 3) void conv_kernel(const signed char* __restrict__ xqT,
                                                      const signed char* __restrict__ Bt,
                                                      const float* __restrict__ bias,
                                                      const float* __restrict__ Esum,
                                                      float* __restrict__ out) {
  __shared__ signed char Bs[BTILE];

  const int t = threadIdx.x;
  const int lane = t & 63;
  const int wid = t >> 6;
  // bijective XCD swizzle: 1568 = 8 * 196; consecutive swizzled ids pair the two
  // N-halves of one M-tile (A reuse within an XCD's L2)
  const int bid = blockIdx.x;
  const int tile = (bid & 7) * 196 + (bid >> 3);
  const int m0 = (tile >> 1) * 128;
  const int n0 = (tile & 1) * 128;
  const int wm = (wid & 1) * 64;
  const int wn = (wid >> 1) * 64;
  const int lrow = lane & 31;
  const int half = lane >> 5;          // 16B K-half within a 32-K mfma block

  // padded pixel base pointers for this lane's two A rows (plane "half" folded in)
  const signed char *ap0, *ap1;
  {
    const int p0 = m0 + wm + lrow;
    const int n_ = p0 / 3136, r_ = p0 - n_ * 3136;
    const int h_ = r_ / 56, w_ = r_ - h_ * 56;
    ap0 = xqT + (long)half * CHB + ((n_ * 58 + h_ + 1) * 58 + (w_ + 1)) * 16;
    const int p1 = p0 + 32;
    const int n2 = p1 / 3136, r2 = p1 - n2 * 3136;
    const int h2 = r2 / 56, w2 = r2 - h2 * 56;
    ap1 = xqT + (long)half * CHB + ((n2 * 58 + h2 + 1) * 58 + (w2 + 1)) * 16;
  }
  // tap displacement in bytes within a plane
  auto dp16 = [](int tap) { return ((tap / 3 - 1) * 58 + (tap % 3) - 1) * 16; };

  // B staging: 16 lanes per 256B row (4 fully-used cache lines per instr)
  const int brow = t >> 4;             // +16*i, i<8 -> 128 rows
  const int bcol = (t & 15) * 16;
  const int gb0 = (n0 + brow) * KTAP + bcol;
  const int lb0 = brow * LDB + bcol;

  int16v acc[2][2];
#pragma unroll
  for (int a = 0; a < 2; ++a)
#pragma unroll
    for (int b = 0; b < 2; ++b)
#pragma unroll
      for (int r = 0; r < 16; ++r) acc[a][b][r] = 0;

  // ---- prologue: B(0) in flight, A(s=0,ks=0) fragments in flight ----
  int4v rb[8];
#pragma unroll
  for (int i = 0; i < 8; ++i) rb[i] = *(const int4v*)(Bt + gb0 + i * (16 * KTAP));
  int4v raA0 = *(const int4v*)(ap0 + dp16(0));
  int4v raA1 = *(const int4v*)(ap1 + dp16(0));

  for (int s = 0; s < 9; ++s) {
    if (s) __builtin_amdgcn_s_barrier();     // all waves done reading Bs (reads were
                                             // consumed by MFMAs before this point)
    // write B(s): compiler inserts counted vmcnt for rb only
#pragma unroll
    for (int i = 0; i < 8; ++i) *(int4v*)(Bs + lb0 + i * (16 * LDB)) = rb[i];
    asm volatile("s_waitcnt lgkmcnt(0)" ::: "memory");
    __builtin_amdgcn_sched_barrier(0);
    __builtin_amdgcn_s_barrier();
    __builtin_amdgcn_sched_barrier(0);

    // issue B(s+1) loads; they land during this stage's 32-MFMA compute phase
    if (s + 1 < 9) {
      const int go = (s + 1) * 256;
#pragma unroll
      for (int i = 0; i < 8; ++i)
        rb[i] = *(const int4v*)(Bt + gb0 + go + i * (16 * KTAP));
    }

    const signed char* a0s = ap0 + dp16(s);
    const signed char* a1s = ap1 + dp16(s);
    const int dnx = dp16(s + 1 < 9 ? s + 1 : s);   // next-stage ks=0 (clamped)

#pragma unroll
    for (int ks = 0; ks < 8; ++ks) {
      // prefetch next A pair (ks+1 within stage, or ks=0 of next stage)
      int4v nx0 = *(const int4v*)((ks < 7) ? (a0s + (ks + 1) * (2 * CHB))
                                           : (ap0 + dnx));
      int4v nx1 = *(const int4v*)((ks < 7) ? (a1s + (ks + 1) * (2 * CHB))
                                           : (ap1 + dnx));
      const int ko = ks * 32 + half * 16;
      int4v b0 = *(const int4v*)(Bs + (wn + lrow) * LDB + ko);
      int4v b1 = *(const int4v*)(Bs + (wn + 32 + lrow) * LDB + ko);
      __builtin_amdgcn_s_setprio(1);
      acc[0][0] = __builtin_amdgcn_mfma_i32_32x32x32_i8(raA0, b0, acc[0][0], 0, 0, 0);
      acc[0][1] = __builtin_amdgcn_mfma_i32_32x32x32_i8(raA0, b1, acc[0][1], 0, 0, 0);
      acc[1][0] = __builtin_amdgcn_mfma_i32_32x32x32_i8(raA1, b0, acc[1][0], 0, 0, 0);
      acc[1][1] = __builtin_amdgcn_mfma_i32_32x32x32_i8(raA1, b1, acc[1][1], 0, 0, 0);
      __builtin_amdgcn_s_setprio(0);
      raA0 = nx0; raA1 = nx1;
    }
  }

  // epilogue: out = acc * (E/7) + bias
  const float scale = Esum[0] * (1.0f / (589824.0f * 7.0f));
#pragma unroll
  for (int mt = 0; mt < 2; ++mt)
#pragma unroll
    for (int nt = 0; nt < 2; ++nt) {
      const int col = n0 + wn + nt * 32 + lrow;
      const float bv = bias[col];
#pragma unroll
      for (int r = 0; r < 16; ++r) {
        const int row = (r & 3) + 8 * (r >> 2) + 4 * half;
        const int m = m0 + wm + mt * 32 + row;
        out[(long)m * 256 + col] = (float)acc[mt][nt][r] * scale + bv;
      }
    }
}

extern "C" void kernel_launch(void* const* d_in, const int* in_sizes, int n_in,
                              void* d_out, int out_size, void* d_ws, size_t ws_size,
                              hipStream_t stream) {
  const float* x    = (const float*)d_in[0];
  const float* Wm   = (const float*)d_in[1];
  const float* bias = (const float*)d_in[2];
  float* out = (float*)d_out;

  float* Esum = (float*)d_ws;
  signed char* Bt  = (signed char*)d_ws + 256;                // 589,824 B
  signed char* xqT = (signed char*)d_ws + 256 + 589824;       // 27,557,888 B (16 planes)

  hipMemsetAsync(d_ws, 0, 4, stream);
  hipMemsetAsync(xqT, 0, 27557888, stream);                   // zero halo (and all planes)
  quant_w_kernel<<<dim3(36, 4), 256, 0, stream>>>(Wm, Bt, Esum);
  quant_x_kernel<<<25088, 256, 0, stream>>>(x, xqT);
  conv_kernel<<<1568, 256, 0, stream>>>(xqT, Bt, bias, Esum, out);
}